// Round 13
// baseline (342.519 us; speedup 1.0000x reference)
//
#include <hip/hip_runtime.h>
#include <hip/hip_bf16.h>
#include <stdint.h>

#define DIM   1024
#define NH    16
#define HD    64
#define BATCH 2
#define SEQ   2048
#define MTOK  (BATCH*SEQ)   // 4096

typedef __attribute__((ext_vector_type(8))) short bf16x8;   // 8 bf16 (4 VGPRs)
typedef __attribute__((ext_vector_type(4))) float f32x4;    // MFMA C/D
typedef __attribute__((ext_vector_type(4))) unsigned short us4;

__device__ __forceinline__ unsigned short f2bf(float f) {
  union { __hip_bfloat16 h; unsigned short u; } c;
  c.h = __float2bfloat16(f);   // RNE
  return c.u;
}

// async global->LDS, 16B per lane; LDS dest = wave-uniform base + lane*16 (m97/m104).
__device__ __forceinline__ void gload_lds16(const unsigned short* g, unsigned short* l) {
  __builtin_amdgcn_global_load_lds(
      (const __attribute__((address_space(1))) unsigned int*)(uintptr_t)g,
      (__attribute__((address_space(3))) unsigned int*)(uintptr_t)l,
      16, 0, 0);
}

// ---------------------------------------------------------------- fused casts
__global__ void cast_fused(const float* __restrict__ x,  const float* __restrict__ wq,
                           const float* __restrict__ wk, const float* __restrict__ wv,
                           const float* __restrict__ wo,
                           unsigned short* __restrict__ xb,
                           unsigned short* __restrict__ wqkvb,
                           unsigned short* __restrict__ wob) {
  const float* src; unsigned short* dst; int n;
  switch (blockIdx.y) {
    case 0:  src = x;  dst = xb;                n = MTOK * DIM; break;
    case 1:  src = wq; dst = wqkvb;             n = DIM * DIM;  break;
    case 2:  src = wk; dst = wqkvb +   DIM*DIM; n = DIM * DIM;  break;
    case 3:  src = wv; dst = wqkvb + 2*DIM*DIM; n = DIM * DIM;  break;
    default: src = wo; dst = wob;               n = DIM * DIM;  break;
  }
  int idx = (blockIdx.x * blockDim.x + threadIdx.x) * 4;
  const int stride = gridDim.x * blockDim.x * 4;
  for (; idx < n; idx += stride) {
    float4 v = *reinterpret_cast<const float4*>(src + idx);
    us4 o;
    o[0] = f2bf(v.x); o[1] = f2bf(v.y); o[2] = f2bf(v.z); o[3] = f2bf(v.w);
    *reinterpret_cast<us4*>(dst + idx) = o;
  }
}

// ---------------------------------------------------------------- GEMM (B^T): C[m][n] = sum_k A[m][k]*Bw[n][k]
// m97 structure (unchanged from the PASSing round-7 kernel).
template<int EPI>
__global__ __launch_bounds__(256)
void gemm_bt(const unsigned short* __restrict__ A,
             const unsigned short* __restrict__ Bw,
             int M, int N, int K, int ntn,
             unsigned short* __restrict__ Qb,
             unsigned short* __restrict__ Kb,
             unsigned short* __restrict__ Vt,
             float* __restrict__ Cf) {
  __shared__ __align__(16) unsigned short As[128 * 32];
  __shared__ __align__(16) unsigned short Bs[128 * 32];
  const int tid  = threadIdx.x;
  const int lane = tid & 63;
  const int w    = tid >> 6;
  const int wr   = w >> 1, wc = w & 1;

  const int nwg = gridDim.x;
  const int bid = blockIdx.x;
  const int swz = (nwg & 7) == 0 ? (bid & 7) * (nwg >> 3) + (bid >> 3) : bid;
  const int mt = swz / ntn, nt = swz % ntn;
  const int m0 = mt * 128, n0 = nt * 128;

  const int srow = lane >> 2;
  const int scol = (lane & 3) << 3;
  const unsigned short* Ag = A  + (size_t)(m0 + w*32 + srow) * K + scol;
  const unsigned short* Bg = Bw + (size_t)(n0 + w*32 + srow) * K + scol;
  unsigned short* AsW0 = &As[(w*32     ) * 32];
  unsigned short* AsW1 = &As[(w*32 + 16) * 32];
  unsigned short* BsW0 = &Bs[(w*32     ) * 32];
  unsigned short* BsW1 = &Bs[(w*32 + 16) * 32];

  const int l15 = lane & 15;
  const int g8  = (lane >> 4) << 3;
  f32x4 acc[4][4] = {};

  for (int k0 = 0; k0 < K; k0 += 32) {
    gload_lds16(Ag + k0,                AsW0);
    gload_lds16(Ag + (size_t)16*K + k0, AsW1);
    gload_lds16(Bg + k0,                BsW0);
    gload_lds16(Bg + (size_t)16*K + k0, BsW1);
    __syncthreads();
    bf16x8 af[4], bfr[4];
#pragma unroll
    for (int i = 0; i < 4; ++i)
      af[i] = *(const bf16x8*)&As[(wr*64 + i*16 + l15) * 32 + g8];
#pragma unroll
    for (int j = 0; j < 4; ++j)
      bfr[j] = *(const bf16x8*)&Bs[(wc*64 + j*16 + l15) * 32 + g8];
#pragma unroll
    for (int i = 0; i < 4; ++i)
#pragma unroll
      for (int j = 0; j < 4; ++j)
        acc[i][j] = __builtin_amdgcn_mfma_f32_16x16x32_bf16(af[i], bfr[j], acc[i][j], 0, 0, 0);
    __syncthreads();
  }

  const int r0 = m0 + wr*64 + ((lane >> 4) << 2);
  const int c0 = n0 + wc*64 + l15;
  if (EPI == 0) {
#pragma unroll
    for (int i = 0; i < 4; ++i) {
      const int row = r0 + i*16;
      const int bb  = row >> 11;
      const int tt  = row & (SEQ - 1);
#pragma unroll
      for (int j = 0; j < 4; ++j) {
        const int col   = c0 + j*16;
        const int which = col >> 10;
        const int hh    = (col & 1023) >> 6;
        const int dd    = col & 63;
        const int bhh   = bb * NH + hh;
        if (which == 0) {
#pragma unroll
          for (int r = 0; r < 4; ++r)
            Qb[((size_t)bhh * SEQ + tt + r) * HD + dd] = f2bf(acc[i][j][r] * 0.125f);
        } else if (which == 1) {
#pragma unroll
          for (int r = 0; r < 4; ++r)
            Kb[((size_t)bhh * SEQ + tt + r) * HD + dd] = f2bf(acc[i][j][r]);
        } else {
          us4 ov;
#pragma unroll
          for (int r = 0; r < 4; ++r) ov[r] = f2bf(acc[i][j][r]);
          *reinterpret_cast<us4*>(&Vt[((size_t)bhh * HD + dd) * SEQ + tt]) = ov;
        }
      }
    }
  } else {
#pragma unroll
    for (int i = 0; i < 4; ++i)
#pragma unroll
      for (int j = 0; j < 4; ++j)
#pragma unroll
        for (int r = 0; r < 4; ++r)
          Cf[(size_t)(r0 + i*16 + r) * N + c0 + j*16] = acc[i][j][r];
  }
}

// ---------------------------------------------------------------- flash attention
// Round-9 (resubmitted unmeasured): concurrency fix per r7/r8 counters.
//  * QBLK 32->16: same total softmax/MFMA work, 2x blocks (4096 -> nominal
//    4 waves/SIMD), longest-block critical path halves, VGPR drops (~75).
//  * r8 lesson applied: NO register K/V prefetch (VGPR 156 halved occupancy).
//    K/V loaded inline as in r7; L2/L3-resident.
//  * No __syncthreads (1-wave block; DS pipe in-order; HW-proven correct in r8).
//  * T13 defer-max (THR=8; HW-proven correct in r8). T5 setprio kept (m191).
__global__ __launch_bounds__(64)
void attn_fwd(const unsigned short* __restrict__ Qb,
              const unsigned short* __restrict__ Kb,
              const unsigned short* __restrict__ Vt,
              unsigned short* __restrict__ AO) {
  __shared__ __align__(16) unsigned short P[16 * 72];  // +8 pad -> 2-way conflicts only
  const int lane = threadIdx.x;
  const int l15  = lane & 15;
  const int g    = lane >> 4;
  const int g8   = g << 3;
  const int qt   = gridDim.x - 1 - blockIdx.x;  // long q-tiles scheduled first
  const int q0   = qt * 16;
  const int bh   = blockIdx.y;
  const int b    = bh >> 4, h = bh & 15;

  const unsigned short* Qbh = Qb + (size_t)bh * SEQ * HD;
  const unsigned short* Kbh = Kb + (size_t)bh * SEQ * HD;
  const unsigned short* Vbh = Vt + (size_t)bh * HD * SEQ;

  // Q fragments (A-frag: row = lane&15, k = (lane>>4)*8 within each K=32 chunk)
  bf16x8 qf[2];
#pragma unroll
  for (int dd = 0; dd < 2; ++dd)
    qf[dd] = *(const bf16x8*)&Qbh[(size_t)(q0 + l15) * HD + dd*32 + g8];

  f32x4 o[4] = {};
  float mrun[4], lrun[4];
#pragma unroll
  for (int i = 0; i < 4; ++i) { mrun[i] = -1e30f; lrun[i] = 0.f; }

  const int ntile = q0 / 64 + 1;
  for (int t = 0; t < ntile; ++t) {
    const int k0 = t * 64;
    f32x4 s[4] = {};
#pragma unroll
    for (int dd = 0; dd < 2; ++dd) {
      bf16x8 kf[4];
#pragma unroll
      for (int nn = 0; nn < 4; ++nn)
        kf[nn] = *(const bf16x8*)&Kbh[(size_t)(k0 + nn*16 + l15) * HD + dd*32 + g8];
      __builtin_amdgcn_s_setprio(1);
#pragma unroll
      for (int nn = 0; nn < 4; ++nn)
        s[nn] = __builtin_amdgcn_mfma_f32_16x16x32_bf16(qf[dd], kf[nn], s[nn], 0, 0, 0);
      __builtin_amdgcn_s_setprio(0);
    }
    if (t == ntile - 1) {        // causal mask only on diagonal tile
#pragma unroll
      for (int nn = 0; nn < 4; ++nn) {
        const int kg = k0 + nn*16 + l15;
#pragma unroll
        for (int r = 0; r < 4; ++r) {
          const int qg = q0 + g*4 + r;
          if (kg > qg) s[nn][r] = -1e30f;
        }
      }
    }

    // phase 1: row maxes (S row = (lane>>4)*4+r, col = lane&15 (+nn*16);
    // shfl_xor {1,2,4,8} stays within the 16-lane group -> reduces the row's 64 cols)
    float rmax[4], gmax = -1e30f;
#pragma unroll
    for (int r = 0; r < 4; ++r) {
      float v = fmaxf(fmaxf(s[0][r], s[1][r]), fmaxf(s[2][r], s[3][r]));
      v = fmaxf(v, __shfl_xor(v, 1));
      v = fmaxf(v, __shfl_xor(v, 2));
      v = fmaxf(v, __shfl_xor(v, 4));
      v = fmaxf(v, __shfl_xor(v, 8));
      rmax[r] = v;
      gmax = fmaxf(gmax, v - mrun[r]);
    }
    // T13: wave-uniform rescale decision
    const bool resc = __any(gmax > 8.0f);

    // phase 2: exp + sum (+ conditional rescale)
#pragma unroll
    for (int r = 0; r < 4; ++r) {
      float mnew = mrun[r];
      if (resc) {
        mnew = fmaxf(mrun[r], rmax[r]);
        const float alpha = __expf(mrun[r] - mnew);
        lrun[r] *= alpha;
#pragma unroll
        for (int nn = 0; nn < 4; ++nn) o[nn][r] *= alpha;
        mrun[r] = mnew;
      }
      float rs = 0.f;
#pragma unroll
      for (int nn = 0; nn < 4; ++nn) {
        const float p = __expf(s[nn][r] - mnew);
        s[nn][r] = p;
        rs += p;
      }
      rs += __shfl_xor(rs, 1);
      rs += __shfl_xor(rs, 2);
      rs += __shfl_xor(rs, 4);
      rs += __shfl_xor(rs, 8);
      lrun[r] += rs;
    }

    // P: C-layout -> LDS (no barrier: single wave, DS pipe in-order)
#pragma unroll
    for (int nn = 0; nn < 4; ++nn)
#pragma unroll
      for (int r = 0; r < 4; ++r)
        P[(g*4 + r) * 72 + nn*16 + l15] = f2bf(s[nn][r]);

    // PV: A=P[q][k], B=V[k][d] from Vt[d][t] (contiguous along t)
#pragma unroll
    for (int kk = 0; kk < 2; ++kk) {
      bf16x8 pa = *(const bf16x8*)&P[l15 * 72 + kk*32 + g8];
      __builtin_amdgcn_s_setprio(1);
#pragma unroll
      for (int nn = 0; nn < 4; ++nn) {
        bf16x8 vf = *(const bf16x8*)&Vbh[(size_t)(nn*16 + l15) * SEQ + k0 + kk*32 + g8];
        o[nn] = __builtin_amdgcn_mfma_f32_16x16x32_bf16(pa, vf, o[nn], 0, 0, 0);
      }
      __builtin_amdgcn_s_setprio(0);
    }
  }

  // normalize + store [b*SEQ+t][h*64+d] bf16
#pragma unroll
  for (int r = 0; r < 4; ++r) {
    const float inv = 1.0f / lrun[r];
    const int row = b*SEQ + q0 + g*4 + r;
#pragma unroll
    for (int nn = 0; nn < 4; ++nn)
      AO[(size_t)row * DIM + h*HD + nn*16 + l15] = f2bf(o[nn][r] * inv);
  }
}

// ---------------------------------------------------------------- launch
extern "C" void kernel_launch(void* const* d_in, const int* in_sizes, int n_in,
                              void* d_out, int out_size, void* d_ws, size_t ws_size,
                              hipStream_t stream) {
  (void)in_sizes; (void)n_in; (void)out_size; (void)ws_size;
  const float* x  = (const float*)d_in[0];
  const float* Wq = (const float*)d_in[2];
  const float* Wk = (const float*)d_in[3];
  const float* Wv = (const float*)d_in[4];
  const float* Wo = (const float*)d_in[5];
  float* out = (float*)d_out;

  unsigned short* ws    = (unsigned short*)d_ws;
  unsigned short* x_bf  = ws;
  unsigned short* wqkv  = x_bf  + (size_t)MTOK * DIM;
  unsigned short* wo_bf = wqkv  + (size_t)3 * DIM * DIM;
  unsigned short* Qb    = wo_bf + (size_t)DIM * DIM;
  unsigned short* Kb    = Qb    + (size_t)MTOK * DIM;
  unsigned short* Vt    = Kb    + (size_t)MTOK * DIM;
  unsigned short* AO    = x_bf;   // alias: x_bf dead after gemm_bt<0>

  cast_fused<<<dim3(1024, 5), 256, 0, stream>>>(x, Wq, Wk, Wv, Wo, x_bf, wqkv, wo_bf);

  gemm_bt<0><<<(MTOK/128) * (3*DIM/128), 256, 0, stream>>>(
      x_bf, wqkv, MTOK, 3*DIM, DIM, 3*DIM/128, Qb, Kb, Vt, nullptr);

  attn_fwd<<<dim3(SEQ/16, BATCH*NH), 64, 0, stream>>>(Qb, Kb, Vt, AO);

  gemm_bt<1><<<(MTOK/128) * (DIM/128), 256, 0, stream>>>(
      AO, wo_bf, MTOK, DIM, DIM, DIM/128, nullptr, nullptr, nullptr, out);
}

// Round 14
// 300.686 us; speedup vs baseline: 1.1391x; 1.1391x over previous
//
#include <hip/hip_runtime.h>
#include <hip/hip_bf16.h>
#include <stdint.h>

#define DIM   1024
#define NH    16
#define HD    64
#define BATCH 2
#define SEQ   2048
#define MTOK  (BATCH*SEQ)   // 4096

typedef __attribute__((ext_vector_type(8))) short bf16x8;   // 8 bf16 (4 VGPRs)
typedef __attribute__((ext_vector_type(4))) float f32x4;    // MFMA C/D
typedef __attribute__((ext_vector_type(4))) unsigned short us4;

__device__ __forceinline__ unsigned short f2bf(float f) {
  union { __hip_bfloat16 h; unsigned short u; } c;
  c.h = __float2bfloat16(f);   // RNE
  return c.u;
}

// async global->LDS, 16B per lane; LDS dest = wave-uniform base + lane*16 (m97/m104).
__device__ __forceinline__ void gload_lds16(const unsigned short* g, unsigned short* l) {
  __builtin_amdgcn_global_load_lds(
      (const __attribute__((address_space(1))) unsigned int*)(uintptr_t)g,
      (__attribute__((address_space(3))) unsigned int*)(uintptr_t)l,
      16, 0, 0);
}

// ---------------------------------------------------------------- fused casts
__global__ void cast_fused(const float* __restrict__ x,  const float* __restrict__ wq,
                           const float* __restrict__ wk, const float* __restrict__ wv,
                           const float* __restrict__ wo,
                           unsigned short* __restrict__ xb,
                           unsigned short* __restrict__ wqkvb,
                           unsigned short* __restrict__ wob) {
  const float* src; unsigned short* dst; int n;
  switch (blockIdx.y) {
    case 0:  src = x;  dst = xb;                n = MTOK * DIM; break;
    case 1:  src = wq; dst = wqkvb;             n = DIM * DIM;  break;
    case 2:  src = wk; dst = wqkvb +   DIM*DIM; n = DIM * DIM;  break;
    case 3:  src = wv; dst = wqkvb + 2*DIM*DIM; n = DIM * DIM;  break;
    default: src = wo; dst = wob;               n = DIM * DIM;  break;
  }
  int idx = (blockIdx.x * blockDim.x + threadIdx.x) * 4;
  const int stride = gridDim.x * blockDim.x * 4;
  for (; idx < n; idx += stride) {
    float4 v = *reinterpret_cast<const float4*>(src + idx);
    us4 o;
    o[0] = f2bf(v.x); o[1] = f2bf(v.y); o[2] = f2bf(v.z); o[3] = f2bf(v.w);
    *reinterpret_cast<us4*>(dst + idx) = o;
  }
}

// ---------------------------------------------------------------- GEMM (B^T): C[m][n] = sum_k A[m][k]*Bw[n][k]
// m97 structure (unchanged from the PASSing round-7 kernel).
template<int EPI>
__global__ __launch_bounds__(256)
void gemm_bt(const unsigned short* __restrict__ A,
             const unsigned short* __restrict__ Bw,
             int M, int N, int K, int ntn,
             unsigned short* __restrict__ Qb,
             unsigned short* __restrict__ Kb,
             unsigned short* __restrict__ Vt,
             float* __restrict__ Cf) {
  __shared__ __align__(16) unsigned short As[128 * 32];
  __shared__ __align__(16) unsigned short Bs[128 * 32];
  const int tid  = threadIdx.x;
  const int lane = tid & 63;
  const int w    = tid >> 6;
  const int wr   = w >> 1, wc = w & 1;

  const int nwg = gridDim.x;
  const int bid = blockIdx.x;
  const int swz = (nwg & 7) == 0 ? (bid & 7) * (nwg >> 3) + (bid >> 3) : bid;
  const int mt = swz / ntn, nt = swz % ntn;
  const int m0 = mt * 128, n0 = nt * 128;

  const int srow = lane >> 2;
  const int scol = (lane & 3) << 3;
  const unsigned short* Ag = A  + (size_t)(m0 + w*32 + srow) * K + scol;
  const unsigned short* Bg = Bw + (size_t)(n0 + w*32 + srow) * K + scol;
  unsigned short* AsW0 = &As[(w*32     ) * 32];
  unsigned short* AsW1 = &As[(w*32 + 16) * 32];
  unsigned short* BsW0 = &Bs[(w*32     ) * 32];
  unsigned short* BsW1 = &Bs[(w*32 + 16) * 32];

  const int l15 = lane & 15;
  const int g8  = (lane >> 4) << 3;
  f32x4 acc[4][4] = {};

  for (int k0 = 0; k0 < K; k0 += 32) {
    gload_lds16(Ag + k0,                AsW0);
    gload_lds16(Ag + (size_t)16*K + k0, AsW1);
    gload_lds16(Bg + k0,                BsW0);
    gload_lds16(Bg + (size_t)16*K + k0, BsW1);
    __syncthreads();
    bf16x8 af[4], bfr[4];
#pragma unroll
    for (int i = 0; i < 4; ++i)
      af[i] = *(const bf16x8*)&As[(wr*64 + i*16 + l15) * 32 + g8];
#pragma unroll
    for (int j = 0; j < 4; ++j)
      bfr[j] = *(const bf16x8*)&Bs[(wc*64 + j*16 + l15) * 32 + g8];
#pragma unroll
    for (int i = 0; i < 4; ++i)
#pragma unroll
      for (int j = 0; j < 4; ++j)
        acc[i][j] = __builtin_amdgcn_mfma_f32_16x16x32_bf16(af[i], bfr[j], acc[i][j], 0, 0, 0);
    __syncthreads();
  }

  const int r0 = m0 + wr*64 + ((lane >> 4) << 2);
  const int c0 = n0 + wc*64 + l15;
  if (EPI == 0) {
#pragma unroll
    for (int i = 0; i < 4; ++i) {
      const int row = r0 + i*16;
      const int bb  = row >> 11;
      const int tt  = row & (SEQ - 1);
#pragma unroll
      for (int j = 0; j < 4; ++j) {
        const int col   = c0 + j*16;
        const int which = col >> 10;
        const int hh    = (col & 1023) >> 6;
        const int dd    = col & 63;
        const int bhh   = bb * NH + hh;
        if (which == 0) {
#pragma unroll
          for (int r = 0; r < 4; ++r)
            Qb[((size_t)bhh * SEQ + tt + r) * HD + dd] = f2bf(acc[i][j][r] * 0.125f);
        } else if (which == 1) {
#pragma unroll
          for (int r = 0; r < 4; ++r)
            Kb[((size_t)bhh * SEQ + tt + r) * HD + dd] = f2bf(acc[i][j][r]);
        } else {
          us4 ov;
#pragma unroll
          for (int r = 0; r < 4; ++r) ov[r] = f2bf(acc[i][j][r]);
          *reinterpret_cast<us4*>(&Vt[((size_t)bhh * HD + dd) * SEQ + tt]) = ov;
        }
      }
    }
  } else {
#pragma unroll
    for (int i = 0; i < 4; ++i)
#pragma unroll
      for (int j = 0; j < 4; ++j)
#pragma unroll
        for (int r = 0; r < 4; ++r)
          Cf[(size_t)(r0 + i*16 + r) * N + c0 + j*16] = acc[i][j][r];
  }
}

// ---------------------------------------------------------------- flash attention
// Round-14: in-block split-K per r7/r9 post-mortem (latency-bound; r9 proved
// "more blocks via smaller QBLK" loses because iterations double; this keeps
// r7's iteration count and quadruples waves).
//  * 4 waves/block, QBLK=32 shared q-rows; wave w takes tiles t = w, w+4, ...
//    with PRIVATE online-softmax state (m,l,o). Per-wave loop body = r7's
//    proven code verbatim (inline K/V loads, T13 defer-max, T5 setprio,
//    private P slice -> no per-tile barriers).
//  * End-of-block merge (flash-decoding combine, exact): 2 barriers total.
//    Idle waves (ntile<4) contribute exp(-1e30-M)=0. Merge buffer aliases the
//    dead P region (barrier-separated).
//  * 2048 blocks x 4 waves = 32 waves/CU nominal, VGPR-capped ~16/CU (4/SIMD)
//    = 2x r7 available, ~4x achieved. LDS 33KB -> 4 blocks/CU, matches cap.
__global__ __launch_bounds__(256)
void attn_fwd(const unsigned short* __restrict__ Qb,
              const unsigned short* __restrict__ Kb,
              const unsigned short* __restrict__ Vt,
              unsigned short* __restrict__ AO) {
  // MO[w]: 32 idx x 64 lanes f32 (8KB/wave). First 18.4KB double as per-wave
  // P buffers (32x72 ushort = 4608B each) during the loop.
  __shared__ __align__(16) float MO[4][32 * 64];
  __shared__ float ML[4][2][32];   // [wave][0=m,1=l][row]
  const int tid  = threadIdx.x;
  const int lane = tid & 63;
  const int w    = tid >> 6;       // wave 0..3 (split-K lane)
  const int l15  = lane & 15;
  const int g    = lane >> 4;
  const int g8   = g << 3;
  const int qt   = gridDim.x - 1 - blockIdx.x;  // long q-tiles scheduled first
  const int q0   = qt * 32;
  const int bh   = blockIdx.y;
  const int b    = bh >> 4, h = bh & 15;

  unsigned short* P = reinterpret_cast<unsigned short*>(&MO[0][0]) + w * (32 * 72);

  const unsigned short* Qbh = Qb + (size_t)bh * SEQ * HD;
  const unsigned short* Kbh = Kb + (size_t)bh * SEQ * HD;
  const unsigned short* Vbh = Vt + (size_t)bh * HD * SEQ;

  // Q fragments (A-frag: row = lane&15, k = (lane>>4)*8 within each K=32 chunk)
  bf16x8 qf[2][2];
#pragma unroll
  for (int mm = 0; mm < 2; ++mm)
#pragma unroll
    for (int dd = 0; dd < 2; ++dd)
      qf[mm][dd] = *(const bf16x8*)&Qbh[(size_t)(q0 + mm*16 + l15) * HD + dd*32 + g8];

  f32x4 o[2][4] = {};
  float mrun[8], lrun[8];
#pragma unroll
  for (int i = 0; i < 8; ++i) { mrun[i] = -1e30f; lrun[i] = 0.f; }

  const int ntile = q0 / 64 + 1;
  for (int t = w; t < ntile; t += 4) {     // split-K: wave-strided tiles
    const int k0 = t * 64;
    f32x4 s[2][4] = {};
#pragma unroll
    for (int dd = 0; dd < 2; ++dd) {
      bf16x8 kf[4];
#pragma unroll
      for (int nn = 0; nn < 4; ++nn)
        kf[nn] = *(const bf16x8*)&Kbh[(size_t)(k0 + nn*16 + l15) * HD + dd*32 + g8];
      __builtin_amdgcn_s_setprio(1);
#pragma unroll
      for (int mm = 0; mm < 2; ++mm)
#pragma unroll
        for (int nn = 0; nn < 4; ++nn)
          s[mm][nn] = __builtin_amdgcn_mfma_f32_16x16x32_bf16(qf[mm][dd], kf[nn], s[mm][nn], 0, 0, 0);
      __builtin_amdgcn_s_setprio(0);
    }
    if (t == ntile - 1) {        // causal mask only on diagonal tile
#pragma unroll
      for (int mm = 0; mm < 2; ++mm)
#pragma unroll
        for (int nn = 0; nn < 4; ++nn) {
          const int kg = k0 + nn*16 + l15;
#pragma unroll
          for (int r = 0; r < 4; ++r) {
            const int qg = q0 + mm*16 + g*4 + r;
            if (kg > qg) s[mm][nn][r] = -1e30f;
          }
        }
    }

    // phase 1: row maxes (16-lane-group butterflies stay within the row)
    float rmax[8], gmax = -1e30f;
#pragma unroll
    for (int mm = 0; mm < 2; ++mm)
#pragma unroll
      for (int r = 0; r < 4; ++r) {
        const int ri = mm*4 + r;
        float v = fmaxf(fmaxf(s[mm][0][r], s[mm][1][r]), fmaxf(s[mm][2][r], s[mm][3][r]));
        v = fmaxf(v, __shfl_xor(v, 1));
        v = fmaxf(v, __shfl_xor(v, 2));
        v = fmaxf(v, __shfl_xor(v, 4));
        v = fmaxf(v, __shfl_xor(v, 8));
        rmax[ri] = v;
        gmax = fmaxf(gmax, v - mrun[ri]);
      }
    // T13: wave-uniform rescale decision
    const bool resc = __any(gmax > 8.0f);

    // phase 2: exp + sum (+ conditional rescale)
#pragma unroll
    for (int mm = 0; mm < 2; ++mm)
#pragma unroll
      for (int r = 0; r < 4; ++r) {
        const int ri = mm*4 + r;
        float mnew = mrun[ri];
        if (resc) {
          mnew = fmaxf(mrun[ri], rmax[ri]);
          const float alpha = __expf(mrun[ri] - mnew);
          lrun[ri] *= alpha;
#pragma unroll
          for (int nn = 0; nn < 4; ++nn) o[mm][nn][r] *= alpha;
          mrun[ri] = mnew;
        }
        float rs = 0.f;
#pragma unroll
        for (int nn = 0; nn < 4; ++nn) {
          const float p = __expf(s[mm][nn][r] - mnew);
          s[mm][nn][r] = p;
          rs += p;
        }
        rs += __shfl_xor(rs, 1);
        rs += __shfl_xor(rs, 2);
        rs += __shfl_xor(rs, 4);
        rs += __shfl_xor(rs, 8);
        lrun[ri] += rs;
      }

    // P: C-layout -> private LDS slice (no barrier: per-wave buffer, DS in-order)
#pragma unroll
    for (int mm = 0; mm < 2; ++mm)
#pragma unroll
      for (int nn = 0; nn < 4; ++nn)
#pragma unroll
        for (int r = 0; r < 4; ++r)
          P[(mm*16 + g*4 + r) * 72 + nn*16 + l15] = f2bf(s[mm][nn][r]);

    // PV: A=P[q][k], B=V[k][d] from Vt[d][t] (contiguous along t)
#pragma unroll
    for (int kk = 0; kk < 2; ++kk) {
      bf16x8 pa[2];
#pragma unroll
      for (int mm = 0; mm < 2; ++mm)
        pa[mm] = *(const bf16x8*)&P[(mm*16 + l15) * 72 + kk*32 + g8];
      __builtin_amdgcn_s_setprio(1);
#pragma unroll
      for (int nn = 0; nn < 4; ++nn) {
        bf16x8 vf = *(const bf16x8*)&Vbh[(size_t)(nn*16 + l15) * SEQ + k0 + kk*32 + g8];
#pragma unroll
        for (int mm = 0; mm < 2; ++mm)
          o[mm][nn] = __builtin_amdgcn_mfma_f32_16x16x32_bf16(pa[mm], vf, o[mm][nn], 0, 0, 0);
      }
      __builtin_amdgcn_s_setprio(0);
    }
  }

  // ---- merge the 4 waves' partial (m, l, o) states (flash-decoding combine)
  __syncthreads();   // all P use done before MO overwrite (regions alias)
#pragma unroll
  for (int mm = 0; mm < 2; ++mm)
#pragma unroll
    for (int nn = 0; nn < 4; ++nn)
#pragma unroll
      for (int r = 0; r < 4; ++r)
        MO[w][(mm*16 + nn*4 + r) * 64 + lane] = o[mm][nn][r];
  if (l15 == 0) {
#pragma unroll
    for (int mm = 0; mm < 2; ++mm)
#pragma unroll
      for (int r = 0; r < 4; ++r) {
        ML[w][0][mm*16 + g*4 + r] = mrun[mm*4 + r];
        ML[w][1][mm*16 + g*4 + r] = lrun[mm*4 + r];
      }
  }
  __syncthreads();
  if (w == 0) {
#pragma unroll
    for (int mm = 0; mm < 2; ++mm)
#pragma unroll
      for (int r = 0; r < 4; ++r) {
        const int rowl = mm*16 + g*4 + r;
        float M = fmaxf(fmaxf(ML[0][0][rowl], ML[1][0][rowl]),
                        fmaxf(ML[2][0][rowl], ML[3][0][rowl]));
        float fac[4], lsum = 0.f;
#pragma unroll
        for (int w4 = 0; w4 < 4; ++w4) {
          fac[w4] = __expf(ML[w4][0][rowl] - M);
          lsum += fac[w4] * ML[w4][1][rowl];
        }
        const float inv = 1.0f / lsum;
        const int row = b*SEQ + q0 + rowl;
#pragma unroll
        for (int nn = 0; nn < 4; ++nn) {
          float acc = 0.f;
#pragma unroll
          for (int w4 = 0; w4 < 4; ++w4)
            acc += fac[w4] * MO[w4][(mm*16 + nn*4 + r) * 64 + lane];
          AO[(size_t)row * DIM + h*HD + nn*16 + l15] = f2bf(acc * inv);
        }
      }
  }
}

// ---------------------------------------------------------------- launch
extern "C" void kernel_launch(void* const* d_in, const int* in_sizes, int n_in,
                              void* d_out, int out_size, void* d_ws, size_t ws_size,
                              hipStream_t stream) {
  (void)in_sizes; (void)n_in; (void)out_size; (void)ws_size;
  const float* x  = (const float*)d_in[0];
  const float* Wq = (const float*)d_in[2];
  const float* Wk = (const float*)d_in[3];
  const float* Wv = (const float*)d_in[4];
  const float* Wo = (const float*)d_in[5];
  float* out = (float*)d_out;

  unsigned short* ws    = (unsigned short*)d_ws;
  unsigned short* x_bf  = ws;
  unsigned short* wqkv  = x_bf  + (size_t)MTOK * DIM;
  unsigned short* wo_bf = wqkv  + (size_t)3 * DIM * DIM;
  unsigned short* Qb    = wo_bf + (size_t)DIM * DIM;
  unsigned short* Kb    = Qb    + (size_t)MTOK * DIM;
  unsigned short* Vt    = Kb    + (size_t)MTOK * DIM;
  unsigned short* AO    = x_bf;   // alias: x_bf dead after gemm_bt<0>

  cast_fused<<<dim3(1024, 5), 256, 0, stream>>>(x, Wq, Wk, Wv, Wo, x_bf, wqkv, wo_bf);

  gemm_bt<0><<<(MTOK/128) * (3*DIM/128), 256, 0, stream>>>(
      x_bf, wqkv, MTOK, 3*DIM, DIM, 3*DIM/128, Qb, Kb, Vt, nullptr);

  attn_fwd<<<dim3(SEQ/32, BATCH*NH), 256, 0, stream>>>(Qb, Kb, Vt, AO);

  gemm_bt<1><<<(MTOK/128) * (DIM/128), 256, 0, stream>>>(
      AO, wo_bf, MTOK, DIM, DIM, DIM/128, nullptr, nullptr, nullptr, out);
}